// Round 10
// baseline (478.305 us; speedup 1.0000x reference)
//
#include <hip/hip_runtime.h>

// ---------- problem constants ----------
#define BB 4096
#define NN 25
#define DD 256
#define HH 8
#define DKH 32
#define MM (BB*NN)          // 102400

typedef __bf16 bf16;
typedef bf16 bf16x8 __attribute__((ext_vector_type(8)));
typedef bf16 bf16x4 __attribute__((ext_vector_type(4)));
typedef float f32x4 __attribute__((ext_vector_type(4)));
typedef float f32x16 __attribute__((ext_vector_type(16)));
typedef int   i32x4 __attribute__((ext_vector_type(4)));
typedef _Float16 h16;
typedef h16 h16x2 __attribute__((ext_vector_type(2)));
typedef h16 h16x4 __attribute__((ext_vector_type(4)));
typedef h16 h16x8 __attribute__((ext_vector_type(8)));

// async global->LDS, 16B per lane, LDS dest = wave-uniform base + lane*16
__device__ __forceinline__ void async_load16(const void* g, void* l) {
  __builtin_amdgcn_global_load_lds(
      (const __attribute__((address_space(1))) unsigned int*)g,
      (__attribute__((address_space(3))) unsigned int*)l, 16, 0, 0);
}

#define SCHED_FENCE() __builtin_amdgcn_sched_barrier(0)
#define BARRIER() do { SCHED_FENCE(); __builtin_amdgcn_s_barrier(); SCHED_FENCE(); } while (0)

// ---------- merged prep: xpad (blocks 0..6911, 16 elems/thread) + tables ----------
__global__ __launch_bounds__(256) void k_prep(
    const float* __restrict__ x, bf16* __restrict__ xpad,
    const float* __restrict__ wq, const float* __restrict__ wk, const float* __restrict__ wv,
    const float* __restrict__ rel, const float* __restrict__ lb, const float* __restrict__ wo,
    const void* __restrict__ adj_raw,
    bf16* __restrict__ Wt, h16* __restrict__ woF, float* __restrict__ mbF2) {
  if (blockIdx.x < 6912) {
    int idx = (blockIdx.x * 256 + threadIdx.x) * 16;   // 16 elems/thread
    int b = idx / 6912;                                // 27*256 per batch
    int rem = idx - b * 6912;
    int j = rem >> 8;
    int d = rem & 255;
    bf16x8 o0, o1;
    if (j >= 1 && j <= 25) {
      const float* src = x + ((b * 25 + (j - 1)) * 256 + d);
      f32x4 v0 = *(const f32x4*)(src);
      f32x4 v1 = *(const f32x4*)(src + 4);
      f32x4 v2 = *(const f32x4*)(src + 8);
      f32x4 v3 = *(const f32x4*)(src + 12);
      #pragma unroll
      for (int t = 0; t < 4; ++t) { o0[t] = (bf16)v0[t]; o0[4 + t] = (bf16)v1[t]; }
      #pragma unroll
      for (int t = 0; t < 4; ++t) { o1[t] = (bf16)v2[t]; o1[4 + t] = (bf16)v3[t]; }
    } else {
      #pragma unroll
      for (int t = 0; t < 8; ++t) { o0[t] = (bf16)0.0f; o1[t] = (bf16)0.0f; }
    }
    *(bf16x8*)(xpad + idx) = o0;
    *(bf16x8*)(xpad + idx + 8) = o1;
    return;
  }
  // ---- table part: 512 blocks grid-stride ----
  const unsigned char* abytes = (const unsigned char*)adj_raw;
  bool anyb = false;
  {
    const int ln = threadIdx.x & 63;
    #pragma unroll
    for (int t = 0; t < 10; ++t) {
      int s = ln + t * 64;
      if (s < 625 && (s & 3) && abytes[s]) anyb = true;
    }
  }
  const bool u8 = __any(anyb);

  const int NWT = 768 * 768;
  const int NMB = HH * 64 * 16;         // 8192 (mbF2)
  const int NWF = 8 * 16 * 64 * 8;      // 65536
  const int total = NWT + NMB + NWF;
  for (int i = (blockIdx.x - 6912) * 256 + threadIdx.x; i < total; i += 512 * 256) {
    if (i < NWT) {
      int j = i / 768, kk = i - j * 768;
      int proj = j >> 8, jo = j & 255;
      int tap = kk >> 8, di = kk & 255;
      const float* w = (proj == 0) ? wq : ((proj == 1) ? wk : wv);
      Wt[i] = (bf16)w[(jo * 256 + di) * 3 + tap];   // w[d_out][d_in][tap]
    } else if (i < NWT + NMB) {
      int t = i - NWT;
      int h = t >> 10;
      int L = (t >> 4) & 63;
      int r = t & 15;
      int iq = L & 31;
      int m = (r & 3) + 8 * (r >> 2) + 4 * (L >> 5);
      float v;
      if (m >= 25) {
        v = -1e30f;
      } else if (iq >= 25) {
        v = 0.0f;
      } else {
        int amask = u8 ? (abytes[iq * 25 + m] ? 1 : 0)
                       : (((const int*)adj_raw)[iq * 25 + m] ? 1 : 0);
        v = amask ? (rel[(iq - m + 24) * HH + h] + lb[h * 625 + iq * 25 + m]) : -1e30f;
      }
      mbF2[t] = v;
    } else {
      int e = i - NWT - NMB;
      int c = e & 7, ln = (e >> 3) & 63, nt = (e >> 9) & 15, ks = e >> 13;
      int col = nt * 16 + (ln & 15);
      int k = ks * 32 + (ln >> 4) * 8 + c;
      woF[e] = (h16)wo[col * 256 + k];
    }
  }
}

// ---------- QKV GEMM + fused LN/residual epilogue ----------
// K-loop unchanged (verified). NEW epilogue: each block's 256-col C-tile is
// exactly one projection (n0/256 = p), so LN-over-256 is block-local:
//   (1) per-wave row partials (4-j adds + shfl_xor over t16) -> LDS[256][4]
//   (2) barrier; combine 4 wc partials -> mu, rsqrt per row (f32 acc — MORE
//       accurate than the old bf16-roundtrip LN)
//   (3) normalize + gamma/beta + x residual (f32), write conv as f16 with the
//       (n&3)<<4 byte-swizzle PRE-APPLIED (XOR of bits 4-5 stays within the
//       32B store segments the C-write already used -> no coalescing change).
// This deletes the attn kernel's entire LN phase and its 105 MB x re-read.
__global__ __launch_bounds__(512, 2) void k_qkv_gemm8(
    const bf16* __restrict__ xpad, const bf16* __restrict__ Wt,
    const float* __restrict__ x,
    const float* __restrict__ gq, const float* __restrict__ bq,
    const float* __restrict__ gk, const float* __restrict__ bk,
    const float* __restrict__ gv, const float* __restrict__ bv,
    h16* __restrict__ conv) {
  __shared__ bf16 Ab[2][256 * 64];
  __shared__ bf16 Bb[2][256 * 64];

  const int L = blockIdx.x;
  const int sw = (L & 7) * 150 + (L >> 3);
  const int n0 = (sw % 3) * 256;
  const int m0 = (sw / 3) * 256;

  const int tid = threadIdx.x;
  const int lane = tid & 63, wave = tid >> 6;
  const int t16 = lane & 15, quad = lane >> 4;
  const int wr = wave >> 2, wc = wave & 3;

  const int srow = tid >> 3;                                    // 0..63
  const int sc = ((tid & 7) << 4) ^ ((srow & 7) << 4);          // pre-swizzled byte col
  int aOff[4], bOff[4];
  #pragma unroll
  for (int q = 0; q < 4; ++q) {
    int row = q * 64 + srow;
    int gm = m0 + row;
    int b = gm / 25;
    int n = gm - b * 25;
    aOff[q] = (b * 27 + n) * 512 + sc;                          // bytes into xpad
    bOff[q] = (n0 + row) * 1536 + sc;                           // bytes into Wt
  }

  const int axr = (t16 & 7) << 3;                               // element-space swizzle
  int aoffs[2], boffs[2];
  #pragma unroll
  for (int kk = 0; kk < 2; ++kk) {
    aoffs[kk] = (wr * 128 + t16) * 64 + ((kk * 32 + quad * 8) ^ axr);
    boffs[kk] = (wc * 64 + t16) * 64 + ((kk * 32 + quad * 8) ^ axr);
  }

  f32x4 acc[8][4];
  #pragma unroll
  for (int i = 0; i < 8; ++i)
    #pragma unroll
    for (int j = 0; j < 4; ++j) acc[i][j] = (f32x4){0.f, 0.f, 0.f, 0.f};

  #define ST_B(bufi, tt) do {                                              \
    char* lb_ = (char*)&Bb[bufi][0] + wave * 1024;                         \
    _Pragma("unroll")                                                      \
    for (int q_ = 0; q_ < 4; ++q_)                                         \
      async_load16((const char*)Wt + bOff[q_] + (tt) * 128, lb_ + q_ * 8192); \
  } while (0)
  #define ST_A(bufi, tt) do {                                              \
    char* la_ = (char*)&Ab[bufi][0] + wave * 1024;                         \
    const int ka_ = ((tt) >> 2) * 512 + ((tt) & 3) * 128;                  \
    _Pragma("unroll")                                                      \
    for (int q_ = 0; q_ < 4; ++q_)                                         \
      async_load16((const char*)xpad + aOff[q_] + ka_, la_ + q_ * 8192);   \
  } while (0)

  ST_B(0, 0); ST_A(0, 0);
  ST_B(1, 1); ST_A(1, 1);
  asm volatile("s_waitcnt vmcnt(8)" ::: "memory");
  SCHED_FENCE();
  BARRIER();

  bf16x8 aLo[8], aHi[8], bLo[4], bHi[4];
  {
    const bf16* Ac = &Ab[0][0];
    const bf16* Bc = &Bb[0][0];
    #pragma unroll
    for (int i = 0; i < 4; ++i)
      #pragma unroll
      for (int kk = 0; kk < 2; ++kk)
        aLo[i * 2 + kk] = *(const bf16x8*)(Ac + aoffs[kk] + i * 1024);
    #pragma unroll
    for (int j = 0; j < 2; ++j)
      #pragma unroll
      for (int kk = 0; kk < 2; ++kk)
        bLo[j * 2 + kk] = *(const bf16x8*)(Bc + boffs[kk] + j * 1024);
  }
  SCHED_FENCE();

  for (int u = 0; u < 12; ++u) {
    const int buf = u & 1;
    const bf16* Ac = &Ab[buf][0];
    const bf16* Bc = &Bb[buf][0];
    const bf16* Ac2 = &Ab[buf ^ 1][0];
    const bf16* Bc2 = &Bb[buf ^ 1][0];
    const int st = u + 2;

    // P0: issue bHi reads; MFMA (0,0)
    #pragma unroll
    for (int j = 0; j < 2; ++j)
      #pragma unroll
      for (int kk = 0; kk < 2; ++kk)
        bHi[j * 2 + kk] = *(const bf16x8*)(Bc + boffs[kk] + (2 + j) * 1024);
    SCHED_FENCE();
    __builtin_amdgcn_s_setprio(1);
    #pragma unroll
    for (int i = 0; i < 4; ++i)
      #pragma unroll
      for (int j = 0; j < 2; ++j)
        #pragma unroll
        for (int kk = 0; kk < 2; ++kk)
          acc[i][j] = __builtin_amdgcn_mfma_f32_16x16x32_bf16(
              aLo[i * 2 + kk], bLo[j * 2 + kk], acc[i][j], 0, 0, 0);
    __builtin_amdgcn_s_setprio(0);
    SCHED_FENCE();

    // P1: issue aHi reads; MFMA (0,1)
    #pragma unroll
    for (int i = 0; i < 4; ++i)
      #pragma unroll
      for (int kk = 0; kk < 2; ++kk)
        aHi[i * 2 + kk] = *(const bf16x8*)(Ac + aoffs[kk] + (4 + i) * 1024);
    SCHED_FENCE();
    __builtin_amdgcn_s_setprio(1);
    #pragma unroll
    for (int i = 0; i < 4; ++i)
      #pragma unroll
      for (int j = 0; j < 2; ++j)
        #pragma unroll
        for (int kk = 0; kk < 2; ++kk)
          acc[i][2 + j] = __builtin_amdgcn_mfma_f32_16x16x32_bf16(
              aLo[i * 2 + kk], bHi[j * 2 + kk], acc[i][2 + j], 0, 0, 0);
    __builtin_amdgcn_s_setprio(0);
    SCHED_FENCE();

    // P2: barrier (B-region safe); stage B(u+2); MFMA (1,0)
    BARRIER();
    if (st < 12) ST_B(buf, st);
    SCHED_FENCE();
    __builtin_amdgcn_s_setprio(1);
    #pragma unroll
    for (int i = 0; i < 4; ++i)
      #pragma unroll
      for (int j = 0; j < 2; ++j)
        #pragma unroll
        for (int kk = 0; kk < 2; ++kk)
          acc[4 + i][j] = __builtin_amdgcn_mfma_f32_16x16x32_bf16(
              aHi[i * 2 + kk], bLo[j * 2 + kk], acc[4 + i][j], 0, 0, 0);
    __builtin_amdgcn_s_setprio(0);
    SCHED_FENCE();

    // P3: counted vmcnt + barrier; stage A(u+2); pre-issue next aLo/bLo; MFMA (1,1)
    if (u < 11) {
      if (u < 10) {
        asm volatile("s_waitcnt vmcnt(4)" ::: "memory");
      } else {
        asm volatile("s_waitcnt vmcnt(0)" ::: "memory");
      }
      SCHED_FENCE();
      BARRIER();
      if (st < 12) ST_A(buf, st);
      #pragma unroll
      for (int i = 0; i < 4; ++i)
        #pragma unroll
        for (int kk = 0; kk < 2; ++kk)
          aLo[i * 2 + kk] = *(const bf16x8*)(Ac2 + aoffs[kk] + i * 1024);
      #pragma unroll
      for (int j = 0; j < 2; ++j)
        #pragma unroll
        for (int kk = 0; kk < 2; ++kk)
          bLo[j * 2 + kk] = *(const bf16x8*)(Bc2 + boffs[kk] + j * 1024);
      SCHED_FENCE();
    }
    __builtin_amdgcn_s_setprio(1);
    #pragma unroll
    for (int i = 0; i < 4; ++i)
      #pragma unroll
      for (int j = 0; j < 2; ++j)
        #pragma unroll
        for (int kk = 0; kk < 2; ++kk)
          acc[4 + i][2 + j] = __builtin_amdgcn_mfma_f32_16x16x32_bf16(
              aHi[i * 2 + kk], bHi[j * 2 + kk], acc[4 + i][2 + j], 0, 0, 0);
    __builtin_amdgcn_s_setprio(0);
    SCHED_FENCE();
  }
  #undef ST_A
  #undef ST_B

  // ---- fused LN + residual epilogue ----
  BARRIER();                               // all waves done with LDS -> reuse Ab
  float* Ps = (float*)&Ab[0][0];           // [256][4] row-sum partials per wc
  float* Qs = Ps + 1024;                   // [256][4] row-sumsq partials
  #pragma unroll
  for (int i = 0; i < 8; ++i)
    #pragma unroll
    for (int r = 0; r < 4; ++r) {
      float s  = acc[i][0][r] + acc[i][1][r] + acc[i][2][r] + acc[i][3][r];
      float ss = acc[i][0][r] * acc[i][0][r] + acc[i][1][r] * acc[i][1][r]
               + acc[i][2][r] * acc[i][2][r] + acc[i][3][r] * acc[i][3][r];
      #pragma unroll
      for (int o = 1; o < 16; o <<= 1) { s += __shfl_xor(s, o); ss += __shfl_xor(ss, o); }
      if (t16 == 0) {
        const int row = wr * 128 + i * 16 + quad * 4 + r;
        Ps[row * 4 + wc] = s;
        Qs[row * 4 + wc] = ss;
      }
    }
  BARRIER();
  const int proj = n0 >> 8;
  const float* gsel = (proj == 0) ? gq : ((proj == 1) ? gk : gv);
  const float* bsel = (proj == 0) ? bq : ((proj == 1) ? bk : bv);
  float gv4[4], bv4[4];
  #pragma unroll
  for (int j = 0; j < 4; ++j) {
    const int col = wc * 64 + j * 16 + t16;
    gv4[j] = gsel[col];
    bv4[j] = bsel[col];
  }
  #pragma unroll
  for (int i = 0; i < 8; ++i)
    #pragma unroll
    for (int r = 0; r < 4; ++r) {
      const int row = wr * 128 + i * 16 + quad * 4 + r;
      const int gm = m0 + row;
      const int bb_ = gm / 25;
      const int n = gm - bb_ * 25;
      f32x4 sv = *(const f32x4*)(Ps + row * 4);
      f32x4 qv2 = *(const f32x4*)(Qs + row * 4);
      const float S  = sv[0] + sv[1] + sv[2] + sv[3];
      const float SS = qv2[0] + qv2[1] + qv2[2] + qv2[3];
      const float mu = S * (1.0f / 256.0f);
      const float var = SS * (1.0f / 256.0f) - mu * mu;
      const float rs = rsqrtf(var + 1e-5f);
      const int swz = (n & 3) << 4;
      char* rowbase = (char*)conv + (size_t)gm * 1536 + proj * 512;
      #pragma unroll
      for (int j = 0; j < 4; ++j) {
        const int col = wc * 64 + j * 16 + t16;
        const float xv = x[(size_t)gm * 256 + col];
        const float val = (acc[i][j][r] - mu) * rs * gv4[j] + bv4[j] + xv;
        *(h16*)(rowbase + ((col * 2) ^ swz)) = (h16)val;
      }
    }
}

// ---------- fused MFMA attention + output projection (LN moved into gemm) ----------
// One block per batch, 4 waves. conv already holds LN'd q|k|v in f16 with the
// (n&3)<<4 byte-swizzle pre-applied by the gemm epilogue. Kernel = stage slab
// -> phase 2 (MFMA attention, Ao -> dead q region, alias-free since swizzle
// only touches bits 4-5) -> phase 3 (f16 MFMA vs fragment-ordered woF).
__global__ __launch_bounds__(256, 4) void k_attn_oproj(
    const h16* __restrict__ conv,
    const float* __restrict__ mbF2, const h16* __restrict__ woF,
    const float* __restrict__ bo, float* __restrict__ out) {
  __shared__ h16 Cs[19456];     // 38912 B
  const int b = blockIdx.x;
  const int tid = threadIdx.x;
  const int wave = tid >> 6, lane = tid & 63;

  const char* slab = (const char*)(conv + (size_t)b * 19200);
  for (int c = wave; c < 38; c += 4)
    async_load16(slab + c * 1024 + lane * 16, (char*)Cs + c * 1024);
  asm volatile("s_waitcnt vmcnt(0)" ::: "memory");
  __syncthreads();

  // phase 2: MFMA attention, 2 heads per wave, all 64 lanes
  {
    const int hi = lane >> 5;
    const int dl = lane & 31;
    const int rowc = dl > 24 ? 24 : dl;
    const char* base = (const char*)Cs;
    const float scale = 0.17677669529663687f;  // 1/sqrt(32)

    #pragma unroll 1
    for (int hh = 0; hh < 2; ++hh) {
      const int h = wave * 2 + hh;

      h16x8 aK[2], bQ[2];
      #pragma unroll
      for (int ks = 0; ks < 2; ++ks) {
        const int kb = h * 64 + ks * 32 + hi * 16;
        aK[ks] = *(const h16x8*)(base + rowc * 1536 + ((512 + kb) ^ ((rowc & 3) << 4)));
        bQ[ks] = *(const h16x8*)(base + rowc * 1536 + ((kb) ^ ((rowc & 3) << 4)));
      }
      f32x16 sacc = (f32x16)(0.0f);
      sacc = __builtin_amdgcn_mfma_f32_32x32x16_f16(aK[0], bQ[0], sacc, 0, 0, 0);
      sacc = __builtin_amdgcn_mfma_f32_32x32x16_f16(aK[1], bQ[1], sacc, 0, 0, 0);

      const float* bp = mbF2 + ((h * 64 + lane) << 4);
      f32x4 b4[4];
      #pragma unroll
      for (int c = 0; c < 4; ++c) b4[c] = *(const f32x4*)(bp + 4 * c);
      float p[16];
      #pragma unroll
      for (int r = 0; r < 16; ++r) p[r] = sacc[r] * scale + b4[r >> 2][r & 3];

      float mx = p[0];
      #pragma unroll
      for (int r = 1; r < 16; ++r) mx = fmaxf(mx, p[r]);
      mx = fmaxf(mx, __shfl_xor(mx, 32));
      float sum = 0.f;
      #pragma unroll
      for (int r = 0; r < 16; ++r) { p[r] = __expf(p[r] - mx); sum += p[r]; }
      sum += __shfl_xor(sum, 32);
      const float inv = 1.0f / sum;
      #pragma unroll
      for (int r = 0; r < 16; ++r) p[r] *= inv;

      int c8[8], d8[8];
      #pragma unroll
      for (int k2 = 0; k2 < 8; ++k2) {
        h16x2 t;
        t[0] = (h16)p[2 * k2];
        t[1] = (h16)p[2 * k2 + 1];
        c8[k2] = __builtin_bit_cast(int, t);
      }
      #pragma unroll
      for (int k2 = 0; k2 < 8; ++k2) d8[k2] = __shfl_xor(c8[k2], 32);
      i32x4 f0 = hi ? (i32x4){d8[2], d8[3], c8[2], c8[3]}
                    : (i32x4){c8[0], c8[1], d8[0], d8[1]};
      i32x4 f1 = hi ? (i32x4){d8[6], d8[7], c8[6], c8[7]}
                    : (i32x4){c8[4], c8[5], d8[4], d8[5]};
      h16x8 fragP0 = __builtin_bit_cast(h16x8, f0);
      h16x8 fragP1 = __builtin_bit_cast(h16x8, f1);

      h16x8 vb0, vb1;
      #pragma unroll
      for (int c = 0; c < 8; ++c) {
        const int m0v = hi * 8 + c;
        int m1v = 16 + hi * 8 + c;
        if (m1v > 24) m1v = 24;
        const int cb = 1024 + h * 64 + 2 * dl;
        vb0[c] = *(const h16*)(base + m0v * 1536 + (cb ^ ((m0v & 3) << 4)));
        vb1[c] = *(const h16*)(base + m1v * 1536 + (cb ^ ((m1v & 3) << 4)));
      }

      f32x16 oacc = (f32x16)(0.0f);
      oacc = __builtin_amdgcn_mfma_f32_32x32x16_f16(fragP0, vb0, oacc, 0, 0, 0);
      oacc = __builtin_amdgcn_mfma_f32_32x32x16_f16(fragP1, vb1, oacc, 0, 0, 0);

      // Ao -> dead q region of head h (swizzle stays within 64B group)
      #pragma unroll
      for (int r = 0; r < 16; ++r) {
        const int io = (r & 3) + 8 * (r >> 2) + 4 * hi;
        if (io < 25) {
          const int wb = io * 1536 + ((h * 64 + 2 * dl) ^ ((io & 3) << 4));
          *(h16*)((char*)Cs + wb) = (h16)oacc[r];
        }
      }
    }
  }
  __syncthreads();

  // phase 3: out[25,256] = Ao[25,256] @ wo^T + bo, f16 MFMA, per wave 4 N-tiles
  {
    const int t16 = lane & 15, quad = lane >> 4;
    f32x4 oacc[2][4];
    #pragma unroll
    for (int mt = 0; mt < 2; ++mt)
      #pragma unroll
      for (int jj = 0; jj < 4; ++jj) oacc[mt][jj] = (f32x4){0.f, 0.f, 0.f, 0.f};
    const int arow0 = t16;
    const int arow1 = (16 + t16 > 24) ? 24 : 16 + t16;
    #pragma unroll
    for (int ks = 0; ks < 8; ++ks) {
      h16x8 aF0, aF1;
      {
        const int kb = ks * 64 + quad * 16;
        aF0 = *(const h16x8*)((const char*)Cs + arow0 * 1536 + (kb ^ ((arow0 & 3) << 4)));
        aF1 = *(const h16x8*)((const char*)Cs + arow1 * 1536 + (kb ^ ((arow1 & 3) << 4)));
      }
      #pragma unroll
      for (int jj = 0; jj < 4; ++jj) {
        const h16x8 bF = *(const h16x8*)(woF + ((ks * 16 + wave * 4 + jj) << 9) + lane * 8);
        oacc[0][jj] = __builtin_amdgcn_mfma_f32_16x16x32_f16(aF0, bF, oacc[0][jj], 0, 0, 0);
        oacc[1][jj] = __builtin_amdgcn_mfma_f32_16x16x32_f16(aF1, bF, oacc[1][jj], 0, 0, 0);
      }
    }
    #pragma unroll
    for (int jj = 0; jj < 4; ++jj) {
      const int col = (wave * 4 + jj) * 16 + t16;
      const float bb = bo[col];
      #pragma unroll
      for (int mt = 0; mt < 2; ++mt)
        #pragma unroll
        for (int r = 0; r < 4; ++r) {
          const int row = mt * 16 + quad * 4 + r;
          if (row < 25)
            out[((size_t)b * 25 + row) * 256 + col] = oacc[mt][jj][r] + bb;
        }
    }
  }
}

extern "C" void kernel_launch(void* const* d_in, const int* in_sizes, int n_in,
                              void* d_out, int out_size, void* d_ws, size_t ws_size,
                              hipStream_t stream) {
  (void)in_sizes; (void)n_in; (void)out_size; (void)ws_size;
  const float* x  = (const float*)d_in[0];
  const void*  adj = d_in[1];
  const float* wq = (const float*)d_in[2];
  const float* wk = (const float*)d_in[3];
  const float* wv = (const float*)d_in[4];
  const float* gq = (const float*)d_in[5];
  const float* bq = (const float*)d_in[6];
  const float* gk = (const float*)d_in[7];
  const float* bk = (const float*)d_in[8];
  const float* gv = (const float*)d_in[9];
  const float* bv = (const float*)d_in[10];
  const float* rel = (const float*)d_in[11];
  const float* lb = (const float*)d_in[12];
  const float* wo = (const float*)d_in[13];
  const float* bo = (const float*)d_in[14];
  float* out = (float*)d_out;

  char* ws = (char*)d_ws;
  size_t off = 0;
  auto alloc = [&](size_t bytes) -> void* {
    void* p = ws + off;
    off += (bytes + 255) & ~(size_t)255;
    return p;
  };
  bf16* xpad = (bf16*)alloc((size_t)BB * 27 * 256 * 2);    // 56.6 MB
  h16*  conv = (h16*)alloc((size_t)MM * 768 * 2);          // 157.3 MB (f16, LN'd)
  bf16* Wt   = (bf16*)alloc((size_t)768 * 768 * 2);
  h16*  woF  = (h16*)alloc((size_t)65536 * 2);             // 128 KB fragment-order wo
  float* mbF2 = (float*)alloc((size_t)HH * 64 * 16 * 4);   // 32 KB C-layout bias

  hipLaunchKernelGGL(k_prep, dim3(7424), dim3(256), 0, stream,
                     x, xpad, wq, wk, wv, rel, lb, wo, adj, Wt, woF, mbF2);
  hipLaunchKernelGGL(k_qkv_gemm8, dim3(1200), dim3(512), 0, stream,
                     xpad, Wt, x, gq, bq, gk, bk, gv, bv, conv);
  hipLaunchKernelGGL(k_attn_oproj, dim3(4096), dim3(256), 0, stream,
                     conv, mbF2, woF, bo, out);
}

// Round 11
// 456.932 us; speedup vs baseline: 1.0468x; 1.0468x over previous
//
#include <hip/hip_runtime.h>

// ---------- problem constants ----------
#define BB 4096
#define NN 25
#define DD 256
#define HH 8
#define DKH 32
#define MM (BB*NN)          // 102400

typedef __bf16 bf16;
typedef bf16 bf16x8 __attribute__((ext_vector_type(8)));
typedef bf16 bf16x4 __attribute__((ext_vector_type(4)));
typedef float f32x4 __attribute__((ext_vector_type(4)));
typedef float f32x16 __attribute__((ext_vector_type(16)));
typedef int   i32x4 __attribute__((ext_vector_type(4)));
typedef _Float16 h16;
typedef h16 h16x2 __attribute__((ext_vector_type(2)));
typedef h16 h16x4 __attribute__((ext_vector_type(4)));
typedef h16 h16x8 __attribute__((ext_vector_type(8)));

// async global->LDS, 16B per lane, LDS dest = wave-uniform base + lane*16
__device__ __forceinline__ void async_load16(const void* g, void* l) {
  __builtin_amdgcn_global_load_lds(
      (const __attribute__((address_space(1))) unsigned int*)g,
      (__attribute__((address_space(3))) unsigned int*)l, 16, 0, 0);
}

#define SCHED_FENCE() __builtin_amdgcn_sched_barrier(0)
#define BARRIER() do { SCHED_FENCE(); __builtin_amdgcn_s_barrier(); SCHED_FENCE(); } while (0)

// ---------- merged prep: xpad (blocks 0..6911, 16 elems/thread) + tables ----------
__global__ __launch_bounds__(256) void k_prep(
    const float* __restrict__ x, bf16* __restrict__ xpad,
    const float* __restrict__ wq, const float* __restrict__ wk, const float* __restrict__ wv,
    const float* __restrict__ rel, const float* __restrict__ lb, const float* __restrict__ wo,
    const void* __restrict__ adj_raw,
    bf16* __restrict__ Wt, h16* __restrict__ woF, float* __restrict__ mbF2) {
  if (blockIdx.x < 6912) {
    int idx = (blockIdx.x * 256 + threadIdx.x) * 16;   // 16 elems/thread
    int b = idx / 6912;                                // 27*256 per batch
    int rem = idx - b * 6912;
    int j = rem >> 8;
    int d = rem & 255;
    bf16x8 o0, o1;
    if (j >= 1 && j <= 25) {
      const float* src = x + ((b * 25 + (j - 1)) * 256 + d);
      f32x4 v0 = *(const f32x4*)(src);
      f32x4 v1 = *(const f32x4*)(src + 4);
      f32x4 v2 = *(const f32x4*)(src + 8);
      f32x4 v3 = *(const f32x4*)(src + 12);
      #pragma unroll
      for (int t = 0; t < 4; ++t) { o0[t] = (bf16)v0[t]; o0[4 + t] = (bf16)v1[t]; }
      #pragma unroll
      for (int t = 0; t < 4; ++t) { o1[t] = (bf16)v2[t]; o1[4 + t] = (bf16)v3[t]; }
    } else {
      #pragma unroll
      for (int t = 0; t < 8; ++t) { o0[t] = (bf16)0.0f; o1[t] = (bf16)0.0f; }
    }
    *(bf16x8*)(xpad + idx) = o0;
    *(bf16x8*)(xpad + idx + 8) = o1;
    return;
  }
  // ---- table part: 512 blocks grid-stride ----
  const unsigned char* abytes = (const unsigned char*)adj_raw;
  bool anyb = false;
  {
    const int ln = threadIdx.x & 63;
    #pragma unroll
    for (int t = 0; t < 10; ++t) {
      int s = ln + t * 64;
      if (s < 625 && (s & 3) && abytes[s]) anyb = true;
    }
  }
  const bool u8 = __any(anyb);

  const int NWT = 768 * 768;
  const int NMB = HH * 64 * 16;         // 8192 (mbF2)
  const int NWF = 8 * 16 * 64 * 8;      // 65536
  const int total = NWT + NMB + NWF;
  for (int i = (blockIdx.x - 6912) * 256 + threadIdx.x; i < total; i += 512 * 256) {
    if (i < NWT) {
      int j = i / 768, kk = i - j * 768;
      int proj = j >> 8, jo = j & 255;
      int tap = kk >> 8, di = kk & 255;
      const float* w = (proj == 0) ? wq : ((proj == 1) ? wk : wv);
      Wt[i] = (bf16)w[(jo * 256 + di) * 3 + tap];   // w[d_out][d_in][tap]
    } else if (i < NWT + NMB) {
      int t = i - NWT;
      int h = t >> 10;
      int L = (t >> 4) & 63;
      int r = t & 15;
      int iq = L & 31;
      int m = (r & 3) + 8 * (r >> 2) + 4 * (L >> 5);
      float v;
      if (m >= 25) {
        v = -1e30f;
      } else if (iq >= 25) {
        v = 0.0f;
      } else {
        int amask = u8 ? (abytes[iq * 25 + m] ? 1 : 0)
                       : (((const int*)adj_raw)[iq * 25 + m] ? 1 : 0);
        v = amask ? (rel[(iq - m + 24) * HH + h] + lb[h * 625 + iq * 25 + m]) : -1e30f;
      }
      mbF2[t] = v;
    } else {
      int e = i - NWT - NMB;
      int c = e & 7, ln = (e >> 3) & 63, nt = (e >> 9) & 15, ks = e >> 13;
      int col = nt * 16 + (ln & 15);
      int k = ks * 32 + (ln >> 4) * 8 + c;
      woF[e] = (h16)wo[col * 256 + k];
    }
  }
}

// ---------- QKV GEMM, 256x256 tile, pipelined reads + derived counted waits ----------
// (round-9 version — verified 152 us, MfmaUtil 33.9%, 0 bank conflicts.
//  LN fusion REVERTED: round-10 measured +81 us on the gemm for -50 on attn.)
__global__ __launch_bounds__(512, 2) void k_qkv_gemm8(const bf16* __restrict__ xpad,
                                                      const bf16* __restrict__ Wt,
                                                      bf16* __restrict__ conv) {
  __shared__ bf16 Ab[2][256 * 64];
  __shared__ bf16 Bb[2][256 * 64];

  const int L = blockIdx.x;
  const int sw = (L & 7) * 150 + (L >> 3);
  const int n0 = (sw % 3) * 256;
  const int m0 = (sw / 3) * 256;

  const int tid = threadIdx.x;
  const int lane = tid & 63, wave = tid >> 6;
  const int t16 = lane & 15, quad = lane >> 4;
  const int wr = wave >> 2, wc = wave & 3;

  const int srow = tid >> 3;                                    // 0..63
  const int sc = ((tid & 7) << 4) ^ ((srow & 7) << 4);          // pre-swizzled byte col
  int aOff[4], bOff[4];
  #pragma unroll
  for (int q = 0; q < 4; ++q) {
    int row = q * 64 + srow;
    int gm = m0 + row;
    int b = gm / 25;
    int n = gm - b * 25;
    aOff[q] = (b * 27 + n) * 512 + sc;                          // bytes into xpad
    bOff[q] = (n0 + row) * 1536 + sc;                           // bytes into Wt
  }

  const int axr = (t16 & 7) << 3;                               // element-space swizzle
  int aoffs[2], boffs[2];
  #pragma unroll
  for (int kk = 0; kk < 2; ++kk) {
    aoffs[kk] = (wr * 128 + t16) * 64 + ((kk * 32 + quad * 8) ^ axr);
    boffs[kk] = (wc * 64 + t16) * 64 + ((kk * 32 + quad * 8) ^ axr);
  }

  f32x4 acc[8][4];
  #pragma unroll
  for (int i = 0; i < 8; ++i)
    #pragma unroll
    for (int j = 0; j < 4; ++j) acc[i][j] = (f32x4){0.f, 0.f, 0.f, 0.f};

  #define ST_B(bufi, tt) do {                                              \
    char* lb_ = (char*)&Bb[bufi][0] + wave * 1024;                         \
    _Pragma("unroll")                                                      \
    for (int q_ = 0; q_ < 4; ++q_)                                         \
      async_load16((const char*)Wt + bOff[q_] + (tt) * 128, lb_ + q_ * 8192); \
  } while (0)
  #define ST_A(bufi, tt) do {                                              \
    char* la_ = (char*)&Ab[bufi][0] + wave * 1024;                         \
    const int ka_ = ((tt) >> 2) * 512 + ((tt) & 3) * 128;                  \
    _Pragma("unroll")                                                      \
    for (int q_ = 0; q_ < 4; ++q_)                                         \
      async_load16((const char*)xpad + aOff[q_] + ka_, la_ + q_ * 8192);   \
  } while (0)

  ST_B(0, 0); ST_A(0, 0);
  ST_B(1, 1); ST_A(1, 1);
  asm volatile("s_waitcnt vmcnt(8)" ::: "memory");
  SCHED_FENCE();
  BARRIER();

  bf16x8 aLo[8], aHi[8], bLo[4], bHi[4];
  {
    const bf16* Ac = &Ab[0][0];
    const bf16* Bc = &Bb[0][0];
    #pragma unroll
    for (int i = 0; i < 4; ++i)
      #pragma unroll
      for (int kk = 0; kk < 2; ++kk)
        aLo[i * 2 + kk] = *(const bf16x8*)(Ac + aoffs[kk] + i * 1024);
    #pragma unroll
    for (int j = 0; j < 2; ++j)
      #pragma unroll
      for (int kk = 0; kk < 2; ++kk)
        bLo[j * 2 + kk] = *(const bf16x8*)(Bc + boffs[kk] + j * 1024);
  }
  SCHED_FENCE();

  for (int u = 0; u < 12; ++u) {
    const int buf = u & 1;
    const bf16* Ac = &Ab[buf][0];
    const bf16* Bc = &Bb[buf][0];
    const bf16* Ac2 = &Ab[buf ^ 1][0];
    const bf16* Bc2 = &Bb[buf ^ 1][0];
    const int st = u + 2;

    // P0: issue bHi reads; MFMA (0,0)
    #pragma unroll
    for (int j = 0; j < 2; ++j)
      #pragma unroll
      for (int kk = 0; kk < 2; ++kk)
        bHi[j * 2 + kk] = *(const bf16x8*)(Bc + boffs[kk] + (2 + j) * 1024);
    SCHED_FENCE();
    __builtin_amdgcn_s_setprio(1);
    #pragma unroll
    for (int i = 0; i < 4; ++i)
      #pragma unroll
      for (int j = 0; j < 2; ++j)
        #pragma unroll
        for (int kk = 0; kk < 2; ++kk)
          acc[i][j] = __builtin_amdgcn_mfma_f32_16x16x32_bf16(
              aLo[i * 2 + kk], bLo[j * 2 + kk], acc[i][j], 0, 0, 0);
    __builtin_amdgcn_s_setprio(0);
    SCHED_FENCE();

    // P1: issue aHi reads; MFMA (0,1)
    #pragma unroll
    for (int i = 0; i < 4; ++i)
      #pragma unroll
      for (int kk = 0; kk < 2; ++kk)
        aHi[i * 2 + kk] = *(const bf16x8*)(Ac + aoffs[kk] + (4 + i) * 1024);
    SCHED_FENCE();
    __builtin_amdgcn_s_setprio(1);
    #pragma unroll
    for (int i = 0; i < 4; ++i)
      #pragma unroll
      for (int j = 0; j < 2; ++j)
        #pragma unroll
        for (int kk = 0; kk < 2; ++kk)
          acc[i][2 + j] = __builtin_amdgcn_mfma_f32_16x16x32_bf16(
              aLo[i * 2 + kk], bHi[j * 2 + kk], acc[i][2 + j], 0, 0, 0);
    __builtin_amdgcn_s_setprio(0);
    SCHED_FENCE();

    // P2: barrier (B-region safe); stage B(u+2); MFMA (1,0)
    BARRIER();
    if (st < 12) ST_B(buf, st);
    SCHED_FENCE();
    __builtin_amdgcn_s_setprio(1);
    #pragma unroll
    for (int i = 0; i < 4; ++i)
      #pragma unroll
      for (int j = 0; j < 2; ++j)
        #pragma unroll
        for (int kk = 0; kk < 2; ++kk)
          acc[4 + i][j] = __builtin_amdgcn_mfma_f32_16x16x32_bf16(
              aHi[i * 2 + kk], bLo[j * 2 + kk], acc[4 + i][j], 0, 0, 0);
    __builtin_amdgcn_s_setprio(0);
    SCHED_FENCE();

    // P3: counted vmcnt + barrier; stage A(u+2); pre-issue next aLo/bLo; MFMA (1,1)
    if (u < 11) {
      if (u < 10) {
        asm volatile("s_waitcnt vmcnt(4)" ::: "memory");
      } else {
        asm volatile("s_waitcnt vmcnt(0)" ::: "memory");
      }
      SCHED_FENCE();
      BARRIER();
      if (st < 12) ST_A(buf, st);
      #pragma unroll
      for (int i = 0; i < 4; ++i)
        #pragma unroll
        for (int kk = 0; kk < 2; ++kk)
          aLo[i * 2 + kk] = *(const bf16x8*)(Ac2 + aoffs[kk] + i * 1024);
      #pragma unroll
      for (int j = 0; j < 2; ++j)
        #pragma unroll
        for (int kk = 0; kk < 2; ++kk)
          bLo[j * 2 + kk] = *(const bf16x8*)(Bc2 + boffs[kk] + j * 1024);
      SCHED_FENCE();
    }
    __builtin_amdgcn_s_setprio(1);
    #pragma unroll
    for (int i = 0; i < 4; ++i)
      #pragma unroll
      for (int j = 0; j < 2; ++j)
        #pragma unroll
        for (int kk = 0; kk < 2; ++kk)
          acc[4 + i][2 + j] = __builtin_amdgcn_mfma_f32_16x16x32_bf16(
              aHi[i * 2 + kk], bHi[j * 2 + kk], acc[4 + i][2 + j], 0, 0, 0);
    __builtin_amdgcn_s_setprio(0);
    SCHED_FENCE();
  }
  #undef ST_A
  #undef ST_B

  #pragma unroll
  for (int i = 0; i < 8; ++i)
    #pragma unroll
    for (int j = 0; j < 4; ++j) {
      const int col = n0 + wc * 64 + j * 16 + t16;
      #pragma unroll
      for (int r = 0; r < 4; ++r) {
        const int rowm = m0 + wr * 128 + i * 16 + quad * 4 + r;
        conv[(size_t)rowm * 768 + col] = (bf16)acc[i][j][r];
      }
    }
}

// ---------- fused LN + residual + MFMA attention + output projection ----------
// Round-9 version (verified 137 us, absmax 0.125) + gamma/beta hoist: the six
// f32x4 gamma/beta vectors are lane-fixed, so they are loaded ONCE before the
// LN loop (saves ~36 global loads/thread on the LN critical path).
__global__ __launch_bounds__(256, 4) void k_attn_oproj(
    const bf16* __restrict__ conv, const float* __restrict__ x,
    const float* __restrict__ gq, const float* __restrict__ bq,
    const float* __restrict__ gk, const float* __restrict__ bk,
    const float* __restrict__ gv, const float* __restrict__ bv,
    const float* __restrict__ mbF2, const h16* __restrict__ woF,
    const float* __restrict__ bo, float* __restrict__ out) {
  __shared__ bf16 Cs[19456];     // 38912 B
  const int b = blockIdx.x;
  const int tid = threadIdx.x;
  const int wave = tid >> 6, lane = tid & 63;

  // issue slab stage first
  const char* slab = (const char*)(conv + (size_t)b * 19200);
  for (int c = wave; c < 38; c += 4)
    async_load16(slab + c * 1024 + lane * 16, (char*)Cs + c * 1024);

  // preload x residual + gamma/beta while the stage is in flight
  const int dbase = lane * 4;
  f32x4 gA = *(const f32x4*)(gq + dbase);
  f32x4 gB = *(const f32x4*)(gk + dbase);
  f32x4 gC = *(const f32x4*)(gv + dbase);
  f32x4 bA = *(const f32x4*)(bq + dbase);
  f32x4 bBv = *(const f32x4*)(bk + dbase);
  f32x4 bC = *(const f32x4*)(bv + dbase);
  h16x4 xpre[19];
  #pragma unroll
  for (int k = 0; k < 19; ++k) {
    const int rowi = wave + 4 * k;
    if (rowi < 75) {
      const int n = rowi / 3;
      f32x4 xv = *(const f32x4*)(x + ((size_t)(b * 25 + n)) * 256 + dbase);
      h16x4 t;
      t[0] = (h16)xv[0]; t[1] = (h16)xv[1]; t[2] = (h16)xv[2]; t[3] = (h16)xv[3];
      xpre[k] = t;
    } else {
      xpre[k] = (h16x4){(h16)0.f, (h16)0.f, (h16)0.f, (h16)0.f};
    }
  }

  asm volatile("s_waitcnt vmcnt(0)" ::: "memory");
  __syncthreads();

  // phase 1: LN + residual, 19 fixed iterations, swizzled in-place write
  #pragma unroll
  for (int k = 0; k < 19; ++k) {
    const int rowi = wave + 4 * k;
    if (rowi < 75) {
      const int n = rowi / 3;
      const int p = rowi - n * 3;
      const int rbyte = n * 1536 + p * 512 + lane * 8;
      bf16x4 cv = *(const bf16x4*)((const char*)Cs + rbyte);
      float v0 = (float)cv[0], v1 = (float)cv[1], v2 = (float)cv[2], v3 = (float)cv[3];
      float s = v0 + v1 + v2 + v3;
      float ss = v0 * v0 + v1 * v1 + v2 * v2 + v3 * v3;
      #pragma unroll
      for (int o = 32; o; o >>= 1) {
        s += __shfl_xor(s, o);
        ss += __shfl_xor(ss, o);
      }
      float mu = s * (1.0f / 256.0f);
      float var = ss * (1.0f / 256.0f) - mu * mu;
      float rs = rsqrtf(var + 1e-5f);
      f32x4 gg = (p == 0) ? gA : ((p == 1) ? gB : gC);
      f32x4 b2 = (p == 0) ? bA : ((p == 1) ? bBv : bC);
      h16x4 xh = xpre[k];
      h16x4 o;
      o[0] = (h16)((v0 - mu) * rs * gg[0] + b2[0]) + xh[0];
      o[1] = (h16)((v1 - mu) * rs * gg[1] + b2[1]) + xh[1];
      o[2] = (h16)((v2 - mu) * rs * gg[2] + b2[2]) + xh[2];
      o[3] = (h16)((v3 - mu) * rs * gg[3] + b2[3]) + xh[3];
      const int wbyte = n * 1536 + ((p * 512 + lane * 8) ^ ((n & 3) << 4));
      *(h16x4*)((char*)Cs + wbyte) = o;
    }
  }
  __syncthreads();

  // phase 2: MFMA attention, 2 heads per wave, all 64 lanes
  {
    const int hi = lane >> 5;
    const int dl = lane & 31;
    const int rowc = dl > 24 ? 24 : dl;
    const char* base = (const char*)Cs;
    const float scale = 0.17677669529663687f;  // 1/sqrt(32)

    #pragma unroll 1
    for (int hh = 0; hh < 2; ++hh) {
      const int h = wave * 2 + hh;

      h16x8 aK[2], bQ[2];
      #pragma unroll
      for (int ks = 0; ks < 2; ++ks) {
        const int kb = h * 64 + ks * 32 + hi * 16;
        aK[ks] = *(const h16x8*)(base + rowc * 1536 + ((512 + kb) ^ ((rowc & 3) << 4)));
        bQ[ks] = *(const h16x8*)(base + rowc * 1536 + ((kb) ^ ((rowc & 3) << 4)));
      }
      f32x16 sacc = (f32x16)(0.0f);
      sacc = __builtin_amdgcn_mfma_f32_32x32x16_f16(aK[0], bQ[0], sacc, 0, 0, 0);
      sacc = __builtin_amdgcn_mfma_f32_32x32x16_f16(aK[1], bQ[1], sacc, 0, 0, 0);

      const float* bp = mbF2 + ((h * 64 + lane) << 4);
      f32x4 b4[4];
      #pragma unroll
      for (int c = 0; c < 4; ++c) b4[c] = *(const f32x4*)(bp + 4 * c);
      float p[16];
      #pragma unroll
      for (int r = 0; r < 16; ++r) p[r] = sacc[r] * scale + b4[r >> 2][r & 3];

      float mx = p[0];
      #pragma unroll
      for (int r = 1; r < 16; ++r) mx = fmaxf(mx, p[r]);
      mx = fmaxf(mx, __shfl_xor(mx, 32));
      float sum = 0.f;
      #pragma unroll
      for (int r = 0; r < 16; ++r) { p[r] = __expf(p[r] - mx); sum += p[r]; }
      sum += __shfl_xor(sum, 32);
      const float inv = 1.0f / sum;
      #pragma unroll
      for (int r = 0; r < 16; ++r) p[r] *= inv;

      int c8[8], d8[8];
      #pragma unroll
      for (int k2 = 0; k2 < 8; ++k2) {
        h16x2 t;
        t[0] = (h16)p[2 * k2];
        t[1] = (h16)p[2 * k2 + 1];
        c8[k2] = __builtin_bit_cast(int, t);
      }
      #pragma unroll
      for (int k2 = 0; k2 < 8; ++k2) d8[k2] = __shfl_xor(c8[k2], 32);
      i32x4 f0 = hi ? (i32x4){d8[2], d8[3], c8[2], c8[3]}
                    : (i32x4){c8[0], c8[1], d8[0], d8[1]};
      i32x4 f1 = hi ? (i32x4){d8[6], d8[7], c8[6], c8[7]}
                    : (i32x4){c8[4], c8[5], d8[4], d8[5]};
      h16x8 fragP0 = __builtin_bit_cast(h16x8, f0);
      h16x8 fragP1 = __builtin_bit_cast(h16x8, f1);

      h16x8 vb0, vb1;
      #pragma unroll
      for (int c = 0; c < 8; ++c) {
        const int m0v = hi * 8 + c;
        int m1v = 16 + hi * 8 + c;
        if (m1v > 24) m1v = 24;
        const int cb = 1024 + h * 64 + 2 * dl;
        vb0[c] = *(const h16*)(base + m0v * 1536 + (cb ^ ((m0v & 3) << 4)));
        vb1[c] = *(const h16*)(base + m1v * 1536 + (cb ^ ((m1v & 3) << 4)));
      }

      f32x16 oacc = (f32x16)(0.0f);
      oacc = __builtin_amdgcn_mfma_f32_32x32x16_f16(fragP0, vb0, oacc, 0, 0, 0);
      oacc = __builtin_amdgcn_mfma_f32_32x32x16_f16(fragP1, vb1, oacc, 0, 0, 0);

      // Ao -> dead q region of head h (swizzle stays within 64B group)
      #pragma unroll
      for (int r = 0; r < 16; ++r) {
        const int io = (r & 3) + 8 * (r >> 2) + 4 * hi;
        if (io < 25) {
          const int wb = io * 1536 + ((h * 64 + 2 * dl) ^ ((io & 3) << 4));
          *(h16*)((char*)Cs + wb) = (h16)oacc[r];
        }
      }
    }
  }
  __syncthreads();

  // phase 3: out[25,256] = Ao[25,256] @ wo^T + bo, f16 MFMA, per wave 4 N-tiles
  {
    const int t16 = lane & 15, quad = lane >> 4;
    f32x4 oacc[2][4];
    #pragma unroll
    for (int mt = 0; mt < 2; ++mt)
      #pragma unroll
      for (int jj = 0; jj < 4; ++jj) oacc[mt][jj] = (f32x4){0.f, 0.f, 0.f, 0.f};
    const int arow0 = t16;
    const int arow1 = (16 + t16 > 24) ? 24 : 16 + t16;
    #pragma unroll
    for (int ks = 0; ks < 8; ++ks) {
      h16x8 aF0, aF1;
      {
        const int kb = ks * 64 + quad * 16;
        aF0 = *(const h16x8*)((const char*)Cs + arow0 * 1536 + (kb ^ ((arow0 & 3) << 4)));
        aF1 = *(const h16x8*)((const char*)Cs + arow1 * 1536 + (kb ^ ((arow1 & 3) << 4)));
      }
      #pragma unroll
      for (int jj = 0; jj < 4; ++jj) {
        const h16x8 bF = *(const h16x8*)(woF + ((ks * 16 + wave * 4 + jj) << 9) + lane * 8);
        oacc[0][jj] = __builtin_amdgcn_mfma_f32_16x16x32_f16(aF0, bF, oacc[0][jj], 0, 0, 0);
        oacc[1][jj] = __builtin_amdgcn_mfma_f32_16x16x32_f16(aF1, bF, oacc[1][jj], 0, 0, 0);
      }
    }
    #pragma unroll
    for (int jj = 0; jj < 4; ++jj) {
      const int col = (wave * 4 + jj) * 16 + t16;
      const float bb = bo[col];
      #pragma unroll
      for (int mt = 0; mt < 2; ++mt)
        #pragma unroll
        for (int r = 0; r < 4; ++r) {
          const int row = mt * 16 + quad * 4 + r;
          if (row < 25)
            out[((size_t)b * 25 + row) * 256 + col] = oacc[mt][jj][r] + bb;
        }
    }
  }
}

extern "C" void kernel_launch(void* const* d_in, const int* in_sizes, int n_in,
                              void* d_out, int out_size, void* d_ws, size_t ws_size,
                              hipStream_t stream) {
  (void)in_sizes; (void)n_in; (void)out_size; (void)ws_size;
  const float* x  = (const float*)d_in[0];
  const void*  adj = d_in[1];
  const float* wq = (const float*)d_in[2];
  const float* wk = (const float*)d_in[3];
  const float* wv = (const float*)d_in[4];
  const float* gq = (const float*)d_in[5];
  const float* bq = (const float*)d_in[6];
  const float* gk = (const float*)d_in[7];
  const float* bk = (const float*)d_in[8];
  const float* gv = (const float*)d_in[9];
  const float* bv = (const float*)d_in[10];
  const float* rel = (const float*)d_in[11];
  const float* lb = (const float*)d_in[12];
  const float* wo = (const float*)d_in[13];
  const float* bo = (const float*)d_in[14];
  float* out = (float*)d_out;

  char* ws = (char*)d_ws;
  size_t off = 0;
  auto alloc = [&](size_t bytes) -> void* {
    void* p = ws + off;
    off += (bytes + 255) & ~(size_t)255;
    return p;
  };
  bf16* xpad = (bf16*)alloc((size_t)BB * 27 * 256 * 2);    // 56.6 MB
  bf16* conv = (bf16*)alloc((size_t)MM * 768 * 2);         // 157.3 MB
  bf16* Wt   = (bf16*)alloc((size_t)768 * 768 * 2);
  h16*  woF  = (h16*)alloc((size_t)65536 * 2);             // 128 KB fragment-order wo
  float* mbF2 = (float*)alloc((size_t)HH * 64 * 16 * 4);   // 32 KB C-layout bias

  hipLaunchKernelGGL(k_prep, dim3(7424), dim3(256), 0, stream,
                     x, xpad, wq, wk, wv, rel, lb, wo, adj, Wt, woF, mbF2);
  hipLaunchKernelGGL(k_qkv_gemm8, dim3(1200), dim3(512), 0, stream, xpad, Wt, conv);
  hipLaunchKernelGGL(k_attn_oproj, dim3(4096), dim3(256), 0, stream,
                     conv, x, gq, bq, gk, bk, gv, bv, mbF2, woF, bo, out);
}